// Round 11
// baseline (230.474 us; speedup 1.0000x reference)
//
#include <hip/hip_runtime.h>

#define EPS 1e-5f
// B=64, D=2048, E=64, H1=512, H2=256

typedef __attribute__((ext_vector_type(8))) short short8;
typedef __attribute__((ext_vector_type(4))) float f32x4;

__device__ __forceinline__ float bflo(unsigned u) { return __uint_as_float(u << 16); }
__device__ __forceinline__ float bfhi(unsigned u) { return __uint_as_float(u & 0xffff0000u); }
__device__ __forceinline__ unsigned short f2bf(float f) {
  unsigned u = __float_as_uint(f);
  u = u + 0x7FFFu + ((u >> 16) & 1u);  // RNE
  return (unsigned short)(u >> 16);
}
__device__ __forceinline__ unsigned pack2(float a, float b) {
  return (unsigned)f2bf(a) | ((unsigned)f2bf(b) << 16);
}

// ---------------- prep2: Q(+pbias), R, W2t, t2/c2, Pf-zero (R6-R10 proven) ----------------
__global__ __launch_bounds__(256) void prep2(
    const float* __restrict__ emb, const float* __restrict__ W1,
    const float* __restrict__ g1, const float* __restrict__ v1,
    const float* __restrict__ b1, const float* __restrict__ m1,
    const float* __restrict__ beta1,
    const float* __restrict__ W2,
    const float* __restrict__ g2, const float* __restrict__ v2,
    const float* __restrict__ b2, const float* __restrict__ m2,
    const float* __restrict__ beta2,
    unsigned* __restrict__ Q, unsigned* __restrict__ R,
    unsigned short* __restrict__ W2t,
    float* __restrict__ t2, float* __restrict__ c2, float* __restrict__ Pf) {
  __shared__ float smem[256];
  const int x = blockIdx.x, t = threadIdx.x;
  if (x < 512) {
    const int k0 = x * 4;
    smem[t] = emb[x * 256 + t];  // 4 emb rows, coalesced
    __syncthreads();
    const int h = t * 2;
    const float a0 = g1[h] * rsqrtf(v1[h] + EPS);
    const float a1 = g1[h + 1] * rsqrtf(v1[h + 1] + EPS);
    const float pb0 = a0 * (b1[h] - m1[h]) + beta1[h];
    const float pb1 = a1 * (b1[h + 1] - m1[h + 1]) + beta1[h + 1];
    const float* We = W1 + 2048 * 512;
    float acc0[4], acc1[4];
    #pragma unroll
    for (int k = 0; k < 4; ++k) { acc0[k] = 0.f; acc1[k] = 0.f; }
    #pragma unroll 4
    for (int e = 0; e < 64; ++e) {
      float2 wv = *(const float2*)(We + e * 512 + h);
      #pragma unroll
      for (int k = 0; k < 4; ++k) {
        float ev = smem[k * 64 + e];  // LDS broadcast
        acc0[k] = fmaf(ev, wv.x, acc0[k]);
        acc1[k] = fmaf(ev, wv.y, acc1[k]);
      }
    }
    #pragma unroll
    for (int k = 0; k < 4; ++k) {
      // pbias folded into Q: h1bn = Pf + (Q+pbias) - rep*R
      Q[(k0 + k) * 256 + t] = pack2(a0 * acc0[k] + pb0, a1 * acc1[k] + pb1);
      float2 wv = *(const float2*)(W1 + (size_t)(k0 + k) * 512 + h);
      R[(k0 + k) * 256 + t] = pack2(a0 * wv.x, a1 * wv.y);
    }
  } else if (x < 576) {
    const int h0 = (x - 512) * 8;
    const int o = t;
    unsigned d[4];
    #pragma unroll
    for (int i = 0; i < 4; ++i) {
      float v0 = W2[(h0 + 2 * i) * 256 + o];      // coalesced across o
      float v1_ = W2[(h0 + 2 * i + 1) * 256 + o];
      d[i] = pack2(v0, v1_);
    }
    *(uint4*)(W2t + o * 512 + h0) = make_uint4(d[0], d[1], d[2], d[3]);  // 16B/thread
  } else {
    float tv = g2[t] * rsqrtf(v2[t] + EPS);
    t2[t] = tv;
    c2[t] = tv * (b2[t] - m2[t]) + beta2[t];
    f32x4 z = (f32x4){0.f, 0.f, 0.f, 0.f};
    #pragma unroll 8
    for (int j = 0; j < 32; ++j)
      *(f32x4*)(Pf + ((size_t)(j * 256 + t)) * 4) = z;  // zero 64x512 f32
  }
}

// ---------------- p_gemm: Pf += rep @ R (split-K, atomic f32) — proven ----------------
__global__ __launch_bounds__(256) void p_gemm(
    const float* __restrict__ rep, const unsigned* __restrict__ R,
    float* __restrict__ Pf) {
  __shared__ float red[4][512];
  const int b = blockIdx.x >> 3, ksl = blockIdx.x & 7;
  const int t = threadIdx.x, lane = t & 63, kq = t >> 6;
  const int kbase = ksl * 256 + kq * 64;
  const unsigned* Rp = R + (size_t)kbase * 256 + lane * 4;
  const float* rp = rep + b * 2048 + kbase;
  float acc[8];
  #pragma unroll
  for (int i = 0; i < 8; ++i) acc[i] = 0.f;
  #pragma unroll 8
  for (int k = 0; k < 64; ++k) {
    uint4 rv = *(const uint4*)(Rp + (size_t)k * 256);
    float rk = rp[k];  // wave-uniform scalar
    acc[0] = fmaf(rk, bflo(rv.x), acc[0]); acc[1] = fmaf(rk, bfhi(rv.x), acc[1]);
    acc[2] = fmaf(rk, bflo(rv.y), acc[2]); acc[3] = fmaf(rk, bfhi(rv.y), acc[3]);
    acc[4] = fmaf(rk, bflo(rv.z), acc[4]); acc[5] = fmaf(rk, bfhi(rv.z), acc[5]);
    acc[6] = fmaf(rk, bflo(rv.w), acc[6]); acc[7] = fmaf(rk, bfhi(rv.w), acc[7]);
  }
  *(f32x4*)(&red[kq][lane * 8])     = (f32x4){acc[0], acc[1], acc[2], acc[3]};
  *(f32x4*)(&red[kq][lane * 8 + 4]) = (f32x4){acc[4], acc[5], acc[6], acc[7]};
  __syncthreads();
  {
    const int h = t * 2;
    float s0 = red[0][h] + red[1][h] + red[2][h] + red[3][h];
    float s1 = red[0][h + 1] + red[1][h + 1] + red[2][h + 1] + red[3][h + 1];
    atomicAdd(&Pf[b * 512 + h], s0);
    atomicAdd(&Pf[b * 512 + h + 1], s1);
  }
}

// ---------------- pf2p: pack Pf (f32) -> P (bf16 pairs) ----------------
__global__ __launch_bounds__(256) void pf2p(const float* __restrict__ Pf,
                                            unsigned* __restrict__ P) {
  const int i = blockIdx.x * 256 + threadIdx.x;  // 16384 pairs
  float2 v = *(const float2*)(Pf + 2 * i);
  P[i] = pack2(v.x, v.y);
}

// ---------------- fused main (v9: barrier-free K-loop, wave-private A in regs) ----------------
// Grid 2048 (one k per block) x 256 thr. Block: 64 b-rows x 256 o, K=512 in 8 chunks.
// Wave w owns o-tile [w*64,w*64+64) and generates ALL its own A fragments in registers
// (no LDS, no __syncthreads in the K-loop — waves drift freely, latency self-hides).
// Per chunk-half staging: 4 P + 1 Q + 1 R uint4 (Q/R wave-broadcast). Two staging sets
// (ks0/ks1) + bfr double-buffer, all reloaded one chunk ahead -> every vmcnt counted.
// Regs: 64 AGPR acc + ~130 VGPR (staging 48, afr 16, bfr 32, rb 4, misc) < 256, no spill.
__global__ __launch_bounds__(256, 2) void fused_main(
    const float* __restrict__ rep,
    const unsigned* __restrict__ P,
    const unsigned* __restrict__ Q,
    const unsigned* __restrict__ Rm,
    const unsigned short* __restrict__ W2t,
    const float* __restrict__ t2, const float* __restrict__ c2,
    const float* __restrict__ W3, const float* __restrict__ b3,
    float* __restrict__ out) {
  __shared__ float partial[4][64];

  const int t = threadIdx.x;
  const int w = t >> 6;          // o-tile [w*64, w*64+64)
  const int ln = t & 15;
  const int lq = (t >> 4) & 3;
  const int kg = blockIdx.x;     // 0..2047

  // rb[mi] = rep[b = mi*16+ln][kg]
  float rb[4];
  #pragma unroll
  for (int mi = 0; mi < 4; ++mi)
    rb[mi] = rep[(mi * 16 + ln) * 2048 + kg];

  f32x4 acc[4][4];
  #pragma unroll
  for (int mi = 0; mi < 4; ++mi)
    #pragma unroll
    for (int nj = 0; nj < 4; ++nj) acc[mi][nj] = (f32x4){0.f, 0.f, 0.f, 0.f};

  // staging sets (static indices only — rule #20)
  uint4 pA[4], qA, rA;   // ks = 0
  uint4 pB[4], qB, rB;   // ks = 1
  short8 bfr0[4], bfr1[4];

  auto loadS = [&](int c, int ks, uint4 (&sp)[4], uint4& sq, uint4& sr) {
    const int cb2 = c * 32 + ks * 16 + lq * 4;
    #pragma unroll
    for (int mi = 0; mi < 4; ++mi)
      sp[mi] = *(const uint4*)(P + ((mi * 16 + ln) << 8) + cb2);
    sq = *(const uint4*)(Q + ((size_t)kg << 8) + cb2);   // wave-broadcast
    sr = *(const uint4*)(Rm + ((size_t)kg << 8) + cb2);  // wave-broadcast
  };
  auto loadB = [&](int c, int ks, short8 (&bfr)[4]) {
    #pragma unroll
    for (int nj = 0; nj < 4; ++nj)
      bfr[nj] = *(const short8*)(W2t + (size_t)(w * 64 + nj * 16 + ln) * 512 +
                                 c * 64 + ks * 32 + lq * 8);
  };
  auto packfrag = [&](const uint4& pv, const uint4& qv, const uint4& rv,
                      float rp_) -> short8 {
    unsigned d0, d1, d2, d3;
    float z0, z1;
    z0 = fmaf(-rp_, bflo(rv.x), bflo(pv.x) + bflo(qv.x));
    z1 = fmaf(-rp_, bfhi(rv.x), bfhi(pv.x) + bfhi(qv.x));
    d0 = pack2(fmaxf(z0, 0.f), fmaxf(z1, 0.f));
    z0 = fmaf(-rp_, bflo(rv.y), bflo(pv.y) + bflo(qv.y));
    z1 = fmaf(-rp_, bfhi(rv.y), bfhi(pv.y) + bfhi(qv.y));
    d1 = pack2(fmaxf(z0, 0.f), fmaxf(z1, 0.f));
    z0 = fmaf(-rp_, bflo(rv.z), bflo(pv.z) + bflo(qv.z));
    z1 = fmaf(-rp_, bfhi(rv.z), bfhi(pv.z) + bfhi(qv.z));
    d2 = pack2(fmaxf(z0, 0.f), fmaxf(z1, 0.f));
    z0 = fmaf(-rp_, bflo(rv.w), bflo(pv.w) + bflo(qv.w));
    z1 = fmaf(-rp_, bfhi(rv.w), bfhi(pv.w) + bfhi(qv.w));
    d3 = pack2(fmaxf(z0, 0.f), fmaxf(z1, 0.f));
    uint4 dd = make_uint4(d0, d1, d2, d3);
    return *(short8*)&dd;
  };

  // prologue: chunk0 staging + B fragments in flight
  loadS(0, 0, pA, qA, rA);
  loadS(0, 1, pB, qB, rB);
  loadB(0, 0, bfr0);
  loadB(0, 1, bfr1);

  #pragma unroll 1
  for (int c = 0; c < 8; ++c) {
    // ---- ks = 0 ----
    {
      short8 afr[4];
      #pragma unroll
      for (int mi = 0; mi < 4; ++mi)
        afr[mi] = packfrag(pA[mi], qA, rA, rb[mi]);   // waits counted vmcnt (S0 oldest)
      if (c < 7) loadS(c + 1, 0, pA, qA, rA);         // WAR: reissue after pack reads
      #pragma unroll
      for (int mi = 0; mi < 4; ++mi)
        #pragma unroll
        for (int nj = 0; nj < 4; ++nj)
          acc[mi][nj] = __builtin_amdgcn_mfma_f32_16x16x32_bf16(afr[mi], bfr0[nj], acc[mi][nj], 0, 0, 0);
      if (c < 7) loadB(c + 1, 0, bfr0);               // a full chunk before use
    }
    // ---- ks = 1 ----
    {
      short8 afr[4];
      #pragma unroll
      for (int mi = 0; mi < 4; ++mi)
        afr[mi] = packfrag(pB[mi], qB, rB, rb[mi]);
      if (c < 7) loadS(c + 1, 1, pB, qB, rB);
      #pragma unroll
      for (int mi = 0; mi < 4; ++mi)
        #pragma unroll
        for (int nj = 0; nj < 4; ++nj)
          acc[mi][nj] = __builtin_amdgcn_mfma_f32_16x16x32_bf16(afr[mi], bfr1[nj], acc[mi][nj], 0, 0, 0);
      if (c < 7) loadB(c + 1, 1, bfr1);
    }
  }

  // epilogue: u = relu(t2[o]*acc + c2[o]) * W3[o]; reduce over o (nj and ln)
  float t2v[4], c2v[4], w3v[4];
  #pragma unroll
  for (int nj = 0; nj < 4; ++nj) {
    int o = w * 64 + nj * 16 + ln;
    t2v[nj] = t2[o];
    c2v[nj] = c2[o];
    w3v[nj] = W3[o];
  }
  #pragma unroll
  for (int mi = 0; mi < 4; ++mi) {
    float s[4] = {0.f, 0.f, 0.f, 0.f};
    #pragma unroll
    for (int nj = 0; nj < 4; ++nj)
      #pragma unroll
      for (int r = 0; r < 4; ++r) {
        float u = fmaf(t2v[nj], acc[mi][nj][r], c2v[nj]);
        u = fmaxf(u, 0.f);
        s[r] = fmaf(u, w3v[nj], s[r]);
      }
    #pragma unroll
    for (int r = 0; r < 4; ++r) {
      #pragma unroll
      for (int m = 1; m < 16; m <<= 1) s[r] += __shfl_xor(s[r], m, 64);
    }
    if (ln == 0) {
      #pragma unroll
      for (int r = 0; r < 4; ++r) partial[w][mi * 16 + lq * 4 + r] = s[r];
    }
  }
  __syncthreads();
  if (t < 64) {
    out[t * 2048 + kg] =
        partial[0][t] + partial[1][t] + partial[2][t] + partial[3][t] + b3[0];
  }
}

extern "C" void kernel_launch(void* const* d_in, const int* in_sizes, int n_in,
                              void* d_out, int out_size, void* d_ws, size_t ws_size,
                              hipStream_t stream) {
  const float* rep   = (const float*)d_in[0];
  const float* emb   = (const float*)d_in[1];
  const float* W1    = (const float*)d_in[2];
  const float* b1    = (const float*)d_in[3];
  const float* g1    = (const float*)d_in[4];
  const float* beta1 = (const float*)d_in[5];
  const float* m1    = (const float*)d_in[6];
  const float* v1    = (const float*)d_in[7];
  const float* W2    = (const float*)d_in[8];
  const float* b2    = (const float*)d_in[9];
  const float* g2    = (const float*)d_in[10];
  const float* beta2 = (const float*)d_in[11];
  const float* m2    = (const float*)d_in[12];
  const float* v2    = (const float*)d_in[13];
  const float* W3    = (const float*)d_in[14];
  const float* b3    = (const float*)d_in[15];
  float* out = (float*)d_out;
  char* ws = (char*)d_ws;

  float* Pf            = (float*)(ws + 0);           // 64x512 f32 (128 KB)
  unsigned* P          = (unsigned*)(ws + 131072);   // 64x256 bf16 pairs (64 KB)
  unsigned* Q          = (unsigned*)(ws + 196608);   // 2048x256 pairs (2 MB)
  unsigned* R          = (unsigned*)(ws + 2293760);  // 2048x256 pairs (2 MB)
  unsigned short* W2t  = (unsigned short*)(ws + 4390912);  // 256x512 bf16 (256 KB)
  float* t2            = (float*)(ws + 4653056);     // 256 f32
  float* c2            = (float*)(ws + 4654080);     // 256 f32

  prep2<<<577, 256, 0, stream>>>(emb, W1, g1, v1, b1, m1, beta1, W2, g2, v2,
                                 b2, m2, beta2, Q, R, W2t, t2, c2, Pf);
  p_gemm<<<512, 256, 0, stream>>>(rep, R, Pf);
  pf2p<<<64, 256, 0, stream>>>(Pf, P);
  fused_main<<<2048, 256, 0, stream>>>(rep, P, Q, R, W2t, t2, c2, W3, b3, out);
}

// Round 12
// 166.118 us; speedup vs baseline: 1.3874x; 1.3874x over previous
//
#include <hip/hip_runtime.h>

#define EPS 1e-5f
// B=64, D=2048, E=64, H1=512, H2=256

typedef __attribute__((ext_vector_type(8))) short short8;
typedef __attribute__((ext_vector_type(4))) float f32x4;

__device__ __forceinline__ float bflo(unsigned u) { return __uint_as_float(u << 16); }
__device__ __forceinline__ float bfhi(unsigned u) { return __uint_as_float(u & 0xffff0000u); }
__device__ __forceinline__ unsigned short f2bf(float f) {
  unsigned u = __float_as_uint(f);
  u = u + 0x7FFFu + ((u >> 16) & 1u);  // RNE
  return (unsigned short)(u >> 16);
}
__device__ __forceinline__ unsigned pack2(float a, float b) {
  return (unsigned)f2bf(a) | ((unsigned)f2bf(b) << 16);
}
// HW packed f32->bf16 RNE: 1 instr replaces ~8-op manual pack (gfx950 v_cvt_pk_bf16_f32)
__device__ __forceinline__ unsigned pk_bf16(float lo, float hi) {
  unsigned r;
  asm("v_cvt_pk_bf16_f32 %0, %1, %2" : "=v"(r) : "v"(lo), "v"(hi));
  return r;
}

// ---------------- prep2: Q(+pbias), R, W2t, t2/c2, Pf-zero (R6-R10 proven) ----------------
__global__ __launch_bounds__(256) void prep2(
    const float* __restrict__ emb, const float* __restrict__ W1,
    const float* __restrict__ g1, const float* __restrict__ v1,
    const float* __restrict__ b1, const float* __restrict__ m1,
    const float* __restrict__ beta1,
    const float* __restrict__ W2,
    const float* __restrict__ g2, const float* __restrict__ v2,
    const float* __restrict__ b2, const float* __restrict__ m2,
    const float* __restrict__ beta2,
    unsigned* __restrict__ Q, unsigned* __restrict__ R,
    unsigned short* __restrict__ W2t,
    float* __restrict__ t2, float* __restrict__ c2, float* __restrict__ Pf) {
  __shared__ float smem[256];
  const int x = blockIdx.x, t = threadIdx.x;
  if (x < 512) {
    const int k0 = x * 4;
    smem[t] = emb[x * 256 + t];  // 4 emb rows, coalesced
    __syncthreads();
    const int h = t * 2;
    const float a0 = g1[h] * rsqrtf(v1[h] + EPS);
    const float a1 = g1[h + 1] * rsqrtf(v1[h + 1] + EPS);
    const float pb0 = a0 * (b1[h] - m1[h]) + beta1[h];
    const float pb1 = a1 * (b1[h + 1] - m1[h + 1]) + beta1[h + 1];
    const float* We = W1 + 2048 * 512;
    float acc0[4], acc1[4];
    #pragma unroll
    for (int k = 0; k < 4; ++k) { acc0[k] = 0.f; acc1[k] = 0.f; }
    #pragma unroll 4
    for (int e = 0; e < 64; ++e) {
      float2 wv = *(const float2*)(We + e * 512 + h);
      #pragma unroll
      for (int k = 0; k < 4; ++k) {
        float ev = smem[k * 64 + e];  // LDS broadcast
        acc0[k] = fmaf(ev, wv.x, acc0[k]);
        acc1[k] = fmaf(ev, wv.y, acc1[k]);
      }
    }
    #pragma unroll
    for (int k = 0; k < 4; ++k) {
      // pbias folded into Q: h1bn = Pf + (Q+pbias) - rep*R
      Q[(k0 + k) * 256 + t] = pack2(a0 * acc0[k] + pb0, a1 * acc1[k] + pb1);
      float2 wv = *(const float2*)(W1 + (size_t)(k0 + k) * 512 + h);
      R[(k0 + k) * 256 + t] = pack2(a0 * wv.x, a1 * wv.y);
    }
  } else if (x < 576) {
    const int h0 = (x - 512) * 8;
    const int o = t;
    unsigned d[4];
    #pragma unroll
    for (int i = 0; i < 4; ++i) {
      float v0 = W2[(h0 + 2 * i) * 256 + o];      // coalesced across o
      float v1_ = W2[(h0 + 2 * i + 1) * 256 + o];
      d[i] = pack2(v0, v1_);
    }
    *(uint4*)(W2t + o * 512 + h0) = make_uint4(d[0], d[1], d[2], d[3]);  // 16B/thread
  } else {
    float tv = g2[t] * rsqrtf(v2[t] + EPS);
    t2[t] = tv;
    c2[t] = tv * (b2[t] - m2[t]) + beta2[t];
    f32x4 z = (f32x4){0.f, 0.f, 0.f, 0.f};
    #pragma unroll 8
    for (int j = 0; j < 32; ++j)
      *(f32x4*)(Pf + ((size_t)(j * 256 + t)) * 4) = z;  // zero 64x512 f32
  }
}

// ---------------- p_gemm: Pf += rep @ R (split-K, atomic f32) — proven ----------------
__global__ __launch_bounds__(256) void p_gemm(
    const float* __restrict__ rep, const unsigned* __restrict__ R,
    float* __restrict__ Pf) {
  __shared__ float red[4][512];
  const int b = blockIdx.x >> 3, ksl = blockIdx.x & 7;
  const int t = threadIdx.x, lane = t & 63, kq = t >> 6;
  const int kbase = ksl * 256 + kq * 64;
  const unsigned* Rp = R + (size_t)kbase * 256 + lane * 4;
  const float* rp = rep + b * 2048 + kbase;
  float acc[8];
  #pragma unroll
  for (int i = 0; i < 8; ++i) acc[i] = 0.f;
  #pragma unroll 8
  for (int k = 0; k < 64; ++k) {
    uint4 rv = *(const uint4*)(Rp + (size_t)k * 256);
    float rk = rp[k];  // wave-uniform scalar
    acc[0] = fmaf(rk, bflo(rv.x), acc[0]); acc[1] = fmaf(rk, bfhi(rv.x), acc[1]);
    acc[2] = fmaf(rk, bflo(rv.y), acc[2]); acc[3] = fmaf(rk, bfhi(rv.y), acc[3]);
    acc[4] = fmaf(rk, bflo(rv.z), acc[4]); acc[5] = fmaf(rk, bfhi(rv.z), acc[5]);
    acc[6] = fmaf(rk, bflo(rv.w), acc[6]); acc[7] = fmaf(rk, bfhi(rv.w), acc[7]);
  }
  *(f32x4*)(&red[kq][lane * 8])     = (f32x4){acc[0], acc[1], acc[2], acc[3]};
  *(f32x4*)(&red[kq][lane * 8 + 4]) = (f32x4){acc[4], acc[5], acc[6], acc[7]};
  __syncthreads();
  {
    const int h = t * 2;
    float s0 = red[0][h] + red[1][h] + red[2][h] + red[3][h];
    float s1 = red[0][h + 1] + red[1][h + 1] + red[2][h + 1] + red[3][h + 1];
    atomicAdd(&Pf[b * 512 + h], s0);
    atomicAdd(&Pf[b * 512 + h + 1], s1);
  }
}

// ---------------- pf2p: pack Pf (f32) -> P (bf16 pairs) ----------------
__global__ __launch_bounds__(256) void pf2p(const float* __restrict__ Pf,
                                            unsigned* __restrict__ P) {
  const int i = blockIdx.x * 256 + threadIdx.x;  // 16384 pairs
  float2 v = *(const float2*)(Pf + 2 * i);
  P[i] = pack2(v.x, v.y);
}

// ---------------- fused main (v10: R10/v8 + v_cvt_pk_bf16_f32 in gen pack) ----------------
// Block: 2 k x 64 b = 128 rows, N=256, K=512 in 8 chunks of 64. 4 waves, o-tile 64/wave.
// Queue discipline (R10-proven): genLoad(c+1) < bfr(c,0) < bfr(c,1) < genLoad(c+2);
// every vmcnt in the loop is counted (never 0). Single change vs R10: genStore packs
// via HW v_cvt_pk_bf16_f32 (1 instr / 2 elems, RNE) instead of 8-op manual f2bf —
// halves gen VALU (~224 -> ~112 ops/chunk/thread) on the pre-barrier critical path.
__global__ __launch_bounds__(256, 2) void fused_main(
    const float* __restrict__ rep,
    const unsigned* __restrict__ P,
    const unsigned* __restrict__ Q,
    const unsigned* __restrict__ Rm,
    const unsigned short* __restrict__ W2t,
    const float* __restrict__ t2, const float* __restrict__ c2,
    const float* __restrict__ W3, const float* __restrict__ b3,
    float* __restrict__ out) {
  __shared__ unsigned short A_lds[2][8192];  // 2 x 16KB, fragment-ordered
  __shared__ float partial[4][128];

  const int t = threadIdx.x;
  const int w = t >> 6;
  const int ln = t & 15;
  const int lq = (t >> 4) & 3;
  const int ks_id = w & 1;   // gen role: 32-col half of 64-chunk
  const int hi_id = w >> 1;  // gen role: mi parity
  const int k0 = blockIdx.x * 2;

  // rep scalars for this thread's 4 generated rows (regs, no LDS)
  float rb[4];
  #pragma unroll
  for (int p = 0; p < 4; ++p) {
    int r = (p * 2 + hi_id) * 16 + ln;
    rb[p] = rep[(r & 63) * 2048 + k0 + (r >> 6)];
  }

  f32x4 acc[8][4];
  #pragma unroll
  for (int mi = 0; mi < 8; ++mi)
    #pragma unroll
    for (int nj = 0; nj < 4; ++nj) acc[mi][nj] = (f32x4){0.f, 0.f, 0.f, 0.f};

  // one full chunk of staging: 12 uint4
  uint4 s_p[4], s_q[4], s_r[4];
  // B fragments, double-buffered across half-chunks
  short8 bfr0[4], bfr1[4];

  auto genLoad = [&](int c) {
    const int cb2 = (c * 64 + ks_id * 32 + lq * 8) >> 1;
    #pragma unroll
    for (int p = 0; p < 4; ++p) {
      const int r = (p * 2 + hi_id) * 16 + ln;
      const int bb = r & 63;
      const int kg = k0 + (r >> 6);
      s_p[p] = *(const uint4*)(P + (bb << 8) + cb2);
      s_q[p] = *(const uint4*)(Q + (kg << 8) + cb2);
      s_r[p] = *(const uint4*)(Rm + (kg << 8) + cb2);
    }
  };
  auto genStore = [&](unsigned short* buf) {
    #pragma unroll
    for (int p = 0; p < 4; ++p) {
      const float rp_ = rb[p];
      unsigned d[4];
      float z0, z1;
      z0 = fmaf(-rp_, bflo(s_r[p].x), bflo(s_p[p].x) + bflo(s_q[p].x));
      z1 = fmaf(-rp_, bfhi(s_r[p].x), bfhi(s_p[p].x) + bfhi(s_q[p].x));
      d[0] = pk_bf16(fmaxf(z0, 0.f), fmaxf(z1, 0.f));
      z0 = fmaf(-rp_, bflo(s_r[p].y), bflo(s_p[p].y) + bflo(s_q[p].y));
      z1 = fmaf(-rp_, bfhi(s_r[p].y), bfhi(s_p[p].y) + bfhi(s_q[p].y));
      d[1] = pk_bf16(fmaxf(z0, 0.f), fmaxf(z1, 0.f));
      z0 = fmaf(-rp_, bflo(s_r[p].z), bflo(s_p[p].z) + bflo(s_q[p].z));
      z1 = fmaf(-rp_, bfhi(s_r[p].z), bfhi(s_p[p].z) + bfhi(s_q[p].z));
      d[2] = pk_bf16(fmaxf(z0, 0.f), fmaxf(z1, 0.f));
      z0 = fmaf(-rp_, bflo(s_r[p].w), bflo(s_p[p].w) + bflo(s_q[p].w));
      z1 = fmaf(-rp_, bfhi(s_r[p].w), bfhi(s_p[p].w) + bfhi(s_q[p].w));
      d[3] = pk_bf16(fmaxf(z0, 0.f), fmaxf(z1, 0.f));
      // fragment group id = p*256 + t (== ((mi*2+ks_id)*4+lq)*16+ln, mi=p*2+hi_id)
      *(uint4*)(&buf[(size_t)(p * 256 + t) * 8]) = make_uint4(d[0], d[1], d[2], d[3]);
    }
  };
  auto loadB = [&](int c, int ks, short8 (&bfr)[4]) {
    #pragma unroll
    for (int nj = 0; nj < 4; ++nj)
      bfr[nj] = *(const short8*)(W2t + (size_t)(w * 64 + nj * 16 + ln) * 512 +
                                 c * 64 + ks * 32 + lq * 8);
  };
  auto mfma_half = [&](const unsigned short* buf, int ks, short8 (&bfr)[4]) {
    short8 afr[4];
    #pragma unroll
    for (int mi = 0; mi < 4; ++mi)
      afr[mi] = *(const short8*)(buf + (size_t)((((mi * 2 + ks) * 4 + lq) * 16 + ln) * 8));
    #pragma unroll
    for (int mi = 0; mi < 4; ++mi)
      #pragma unroll
      for (int nj = 0; nj < 4; ++nj)
        acc[mi][nj] = __builtin_amdgcn_mfma_f32_16x16x32_bf16(afr[mi], bfr[nj], acc[mi][nj], 0, 0, 0);
    #pragma unroll
    for (int mi = 0; mi < 4; ++mi)
      afr[mi] = *(const short8*)(buf + (size_t)(((((mi + 4) * 2 + ks) * 4 + lq) * 16 + ln) * 8));
    #pragma unroll
    for (int mi = 0; mi < 4; ++mi)
      #pragma unroll
      for (int nj = 0; nj < 4; ++nj)
        acc[mi + 4][nj] = __builtin_amdgcn_mfma_f32_16x16x32_bf16(afr[mi], bfr[nj], acc[mi + 4][nj], 0, 0, 0);
  };

  // prologue: chunk0 staged (one-time vmcnt stall); chunk1 loads + both bfr(0,*) in flight
  genLoad(0);
  genStore(A_lds[0]);
  genLoad(1);
  loadB(0, 0, bfr0);
  loadB(0, 1, bfr1);

  for (int c = 0; c < 8; ++c) {
    __syncthreads();  // writes of buf[c&1] visible; prior reads of buf[(c+1)&1] done
    if (c < 7) genStore(A_lds[(c + 1) & 1]);  // data loaded a full chunk ago
    if (c < 6) genLoad(c + 2);                // newest in queue; MFMA waits skip it
    const unsigned short* buf = A_lds[c & 1];
    mfma_half(buf, 0, bfr0);
    if (c < 7) loadB(c + 1, 0, bfr0);         // issue a full chunk before use
    mfma_half(buf, 1, bfr1);
    if (c < 7) loadB(c + 1, 1, bfr1);
  }

  // epilogue: u = relu(t2[o]*acc + c2[o]) * W3[o]; reduce over o
  float t2v[4], c2v[4], w3v[4];
  #pragma unroll
  for (int nj = 0; nj < 4; ++nj) {
    int o = w * 64 + nj * 16 + ln;
    t2v[nj] = t2[o];
    c2v[nj] = c2[o];
    w3v[nj] = W3[o];
  }
  #pragma unroll
  for (int mi = 0; mi < 8; ++mi) {
    float s[4] = {0.f, 0.f, 0.f, 0.f};
    #pragma unroll
    for (int nj = 0; nj < 4; ++nj)
      #pragma unroll
      for (int r = 0; r < 4; ++r) {
        float u = fmaf(t2v[nj], acc[mi][nj][r], c2v[nj]);
        u = fmaxf(u, 0.f);
        s[r] = fmaf(u, w3v[nj], s[r]);
      }
    #pragma unroll
    for (int r = 0; r < 4; ++r) {
      #pragma unroll
      for (int m = 1; m < 16; m <<= 1) s[r] += __shfl_xor(s[r], m, 64);
    }
    if (ln == 0) {
      #pragma unroll
      for (int r = 0; r < 4; ++r) partial[w][mi * 16 + lq * 4 + r] = s[r];
    }
  }
  __syncthreads();
  if (t < 128) {
    out[(t & 63) * 2048 + k0 + (t >> 6)] =
        partial[0][t] + partial[1][t] + partial[2][t] + partial[3][t] + b3[0];
  }
}

extern "C" void kernel_launch(void* const* d_in, const int* in_sizes, int n_in,
                              void* d_out, int out_size, void* d_ws, size_t ws_size,
                              hipStream_t stream) {
  const float* rep   = (const float*)d_in[0];
  const float* emb   = (const float*)d_in[1];
  const float* W1    = (const float*)d_in[2];
  const float* b1    = (const float*)d_in[3];
  const float* g1    = (const float*)d_in[4];
  const float* beta1 = (const float*)d_in[5];
  const float* m1    = (const float*)d_in[6];
  const float* v1    = (const float*)d_in[7];
  const float* W2    = (const float*)d_in[8];
  const float* b2    = (const float*)d_in[9];
  const float* g2    = (const float*)d_in[10];
  const float* beta2 = (const float*)d_in[11];
  const float* m2    = (const float*)d_in[12];
  const float* v2    = (const float*)d_in[13];
  const float* W3    = (const float*)d_in[14];
  const float* b3    = (const float*)d_in[15];
  float* out = (float*)d_out;
  char* ws = (char*)d_ws;

  float* Pf            = (float*)(ws + 0);           // 64x512 f32 (128 KB)
  unsigned* P          = (unsigned*)(ws + 131072);   // 64x256 bf16 pairs (64 KB)
  unsigned* Q          = (unsigned*)(ws + 196608);   // 2048x256 pairs (2 MB)
  unsigned* R          = (unsigned*)(ws + 2293760);  // 2048x256 pairs (2 MB)
  unsigned short* W2t  = (unsigned short*)(ws + 4390912);  // 256x512 bf16 (256 KB)
  float* t2            = (float*)(ws + 4653056);     // 256 f32
  float* c2            = (float*)(ws + 4654080);     // 256 f32

  prep2<<<577, 256, 0, stream>>>(emb, W1, g1, v1, b1, m1, beta1, W2, g2, v2,
                                 b2, m2, beta2, Q, R, W2t, t2, c2, Pf);
  p_gemm<<<512, 256, 0, stream>>>(rep, R, Pf);
  pf2p<<<64, 256, 0, stream>>>(Pf, P);
  fused_main<<<1024, 256, 0, stream>>>(rep, P, Q, R, W2t, t2, c2, W3, b3, out);
}

// Round 13
// 160.037 us; speedup vs baseline: 1.4401x; 1.0380x over previous
//
#include <hip/hip_runtime.h>
#include <hip/hip_bf16.h>

#define EPS 1e-5f
// B=64, D=2048, E=64, H1=512, H2=256

typedef __attribute__((ext_vector_type(8))) short short8;
typedef __attribute__((ext_vector_type(4))) float f32x4;

__device__ __forceinline__ float bflo(unsigned u) { return __uint_as_float(u << 16); }
__device__ __forceinline__ float bfhi(unsigned u) { return __uint_as_float(u & 0xffff0000u); }
__device__ __forceinline__ unsigned short f2bf(float f) {
  unsigned u = __float_as_uint(f);
  u = u + 0x7FFFu + ((u >> 16) & 1u);  // RNE
  return (unsigned short)(u >> 16);
}
__device__ __forceinline__ unsigned pack2(float a, float b) {
  return (unsigned)f2bf(a) | ((unsigned)f2bf(b) << 16);
}
// Compiler-scheduled packed f32->bf16 RNE (lowers to v_cvt_pk_bf16_f32 on gfx950).
// NOT inline asm — R12 showed hand-asm cvt_pk perturbs regalloc into scratch spill.
__device__ __forceinline__ unsigned pk2(float lo, float hi) {
  __hip_bfloat162 h = __float22bfloat162_rn(float2{lo, hi});
  union { __hip_bfloat162 h2; unsigned u; } cv;
  cv.h2 = h;
  return cv.u;
}

// ---------------- prep2: Q(+pbias), R, W2t, t2/c2, Pf-zero (R6-R10 proven) ----------------
__global__ __launch_bounds__(256) void prep2(
    const float* __restrict__ emb, const float* __restrict__ W1,
    const float* __restrict__ g1, const float* __restrict__ v1,
    const float* __restrict__ b1, const float* __restrict__ m1,
    const float* __restrict__ beta1,
    const float* __restrict__ W2,
    const float* __restrict__ g2, const float* __restrict__ v2,
    const float* __restrict__ b2, const float* __restrict__ m2,
    const float* __restrict__ beta2,
    unsigned* __restrict__ Q, unsigned* __restrict__ R,
    unsigned short* __restrict__ W2t,
    float* __restrict__ t2, float* __restrict__ c2, float* __restrict__ Pf) {
  __shared__ float smem[256];
  const int x = blockIdx.x, t = threadIdx.x;
  if (x < 512) {
    const int k0 = x * 4;
    smem[t] = emb[x * 256 + t];  // 4 emb rows, coalesced
    __syncthreads();
    const int h = t * 2;
    const float a0 = g1[h] * rsqrtf(v1[h] + EPS);
    const float a1 = g1[h + 1] * rsqrtf(v1[h + 1] + EPS);
    const float pb0 = a0 * (b1[h] - m1[h]) + beta1[h];
    const float pb1 = a1 * (b1[h + 1] - m1[h + 1]) + beta1[h + 1];
    const float* We = W1 + 2048 * 512;
    float acc0[4], acc1[4];
    #pragma unroll
    for (int k = 0; k < 4; ++k) { acc0[k] = 0.f; acc1[k] = 0.f; }
    #pragma unroll 4
    for (int e = 0; e < 64; ++e) {
      float2 wv = *(const float2*)(We + e * 512 + h);
      #pragma unroll
      for (int k = 0; k < 4; ++k) {
        float ev = smem[k * 64 + e];  // LDS broadcast
        acc0[k] = fmaf(ev, wv.x, acc0[k]);
        acc1[k] = fmaf(ev, wv.y, acc1[k]);
      }
    }
    #pragma unroll
    for (int k = 0; k < 4; ++k) {
      // pbias folded into Q: h1bn = Pf + (Q+pbias) - rep*R
      Q[(k0 + k) * 256 + t] = pack2(a0 * acc0[k] + pb0, a1 * acc1[k] + pb1);
      float2 wv = *(const float2*)(W1 + (size_t)(k0 + k) * 512 + h);
      R[(k0 + k) * 256 + t] = pack2(a0 * wv.x, a1 * wv.y);
    }
  } else if (x < 576) {
    const int h0 = (x - 512) * 8;
    const int o = t;
    unsigned d[4];
    #pragma unroll
    for (int i = 0; i < 4; ++i) {
      float v0 = W2[(h0 + 2 * i) * 256 + o];      // coalesced across o
      float v1_ = W2[(h0 + 2 * i + 1) * 256 + o];
      d[i] = pack2(v0, v1_);
    }
    *(uint4*)(W2t + o * 512 + h0) = make_uint4(d[0], d[1], d[2], d[3]);  // 16B/thread
  } else {
    float tv = g2[t] * rsqrtf(v2[t] + EPS);
    t2[t] = tv;
    c2[t] = tv * (b2[t] - m2[t]) + beta2[t];
    f32x4 z = (f32x4){0.f, 0.f, 0.f, 0.f};
    #pragma unroll 8
    for (int j = 0; j < 32; ++j)
      *(f32x4*)(Pf + ((size_t)(j * 256 + t)) * 4) = z;  // zero 64x512 f32
  }
}

// ---------------- p_gemm: Pf += rep @ R (split-K, atomic f32) — proven ----------------
__global__ __launch_bounds__(256) void p_gemm(
    const float* __restrict__ rep, const unsigned* __restrict__ R,
    float* __restrict__ Pf) {
  __shared__ float red[4][512];
  const int b = blockIdx.x >> 3, ksl = blockIdx.x & 7;
  const int t = threadIdx.x, lane = t & 63, kq = t >> 6;
  const int kbase = ksl * 256 + kq * 64;
  const unsigned* Rp = R + (size_t)kbase * 256 + lane * 4;
  const float* rp = rep + b * 2048 + kbase;
  float acc[8];
  #pragma unroll
  for (int i = 0; i < 8; ++i) acc[i] = 0.f;
  #pragma unroll 8
  for (int k = 0; k < 64; ++k) {
    uint4 rv = *(const uint4*)(Rp + (size_t)k * 256);
    float rk = rp[k];  // wave-uniform scalar
    acc[0] = fmaf(rk, bflo(rv.x), acc[0]); acc[1] = fmaf(rk, bfhi(rv.x), acc[1]);
    acc[2] = fmaf(rk, bflo(rv.y), acc[2]); acc[3] = fmaf(rk, bfhi(rv.y), acc[3]);
    acc[4] = fmaf(rk, bflo(rv.z), acc[4]); acc[5] = fmaf(rk, bfhi(rv.z), acc[5]);
    acc[6] = fmaf(rk, bflo(rv.w), acc[6]); acc[7] = fmaf(rk, bfhi(rv.w), acc[7]);
  }
  *(f32x4*)(&red[kq][lane * 8])     = (f32x4){acc[0], acc[1], acc[2], acc[3]};
  *(f32x4*)(&red[kq][lane * 8 + 4]) = (f32x4){acc[4], acc[5], acc[6], acc[7]};
  __syncthreads();
  {
    const int h = t * 2;
    float s0 = red[0][h] + red[1][h] + red[2][h] + red[3][h];
    float s1 = red[0][h + 1] + red[1][h + 1] + red[2][h + 1] + red[3][h + 1];
    atomicAdd(&Pf[b * 512 + h], s0);
    atomicAdd(&Pf[b * 512 + h + 1], s1);
  }
}

// ---------------- pf2p: pack Pf (f32) -> P (bf16 pairs) ----------------
__global__ __launch_bounds__(256) void pf2p(const float* __restrict__ Pf,
                                            unsigned* __restrict__ P) {
  const int i = blockIdx.x * 256 + threadIdx.x;  // 16384 pairs
  float2 v = *(const float2*)(Pf + 2 * i);
  P[i] = pack2(v.x, v.y);
}

// ---------------- fused main (v11: R10 structure + compiler-emitted packed bf16 cvt) ----------------
// Block: 2 k x 64 b = 128 rows, N=256, K=512 in 8 chunks of 64. 4 waves, o-tile 64/wave.
// Queue discipline (R10-proven): genLoad(c+1) < bfr(c,0) < bfr(c,1) < genLoad(c+2);
// every vmcnt in the loop is counted (never 0). Single change vs R10: genStore packs
// via __float22bfloat162_rn (compiler lowers to v_cvt_pk_bf16_f32; R12's inline-asm
// form spilled — WRITE_SIZE 2->10MB — so the conversion must stay compiler-visible).
__global__ __launch_bounds__(256, 2) void fused_main(
    const float* __restrict__ rep,
    const unsigned* __restrict__ P,
    const unsigned* __restrict__ Q,
    const unsigned* __restrict__ Rm,
    const unsigned short* __restrict__ W2t,
    const float* __restrict__ t2, const float* __restrict__ c2,
    const float* __restrict__ W3, const float* __restrict__ b3,
    float* __restrict__ out) {
  __shared__ unsigned short A_lds[2][8192];  // 2 x 16KB, fragment-ordered
  __shared__ float partial[4][128];

  const int t = threadIdx.x;
  const int w = t >> 6;
  const int ln = t & 15;
  const int lq = (t >> 4) & 3;
  const int ks_id = w & 1;   // gen role: 32-col half of 64-chunk
  const int hi_id = w >> 1;  // gen role: mi parity
  const int k0 = blockIdx.x * 2;

  // rep scalars for this thread's 4 generated rows (regs, no LDS)
  float rb[4];
  #pragma unroll
  for (int p = 0; p < 4; ++p) {
    int r = (p * 2 + hi_id) * 16 + ln;
    rb[p] = rep[(r & 63) * 2048 + k0 + (r >> 6)];
  }

  f32x4 acc[8][4];
  #pragma unroll
  for (int mi = 0; mi < 8; ++mi)
    #pragma unroll
    for (int nj = 0; nj < 4; ++nj) acc[mi][nj] = (f32x4){0.f, 0.f, 0.f, 0.f};

  // one full chunk of staging: 12 uint4
  uint4 s_p[4], s_q[4], s_r[4];
  // B fragments, double-buffered across half-chunks
  short8 bfr0[4], bfr1[4];

  auto genLoad = [&](int c) {
    const int cb2 = (c * 64 + ks_id * 32 + lq * 8) >> 1;
    #pragma unroll
    for (int p = 0; p < 4; ++p) {
      const int r = (p * 2 + hi_id) * 16 + ln;
      const int bb = r & 63;
      const int kg = k0 + (r >> 6);
      s_p[p] = *(const uint4*)(P + (bb << 8) + cb2);
      s_q[p] = *(const uint4*)(Q + (kg << 8) + cb2);
      s_r[p] = *(const uint4*)(Rm + (kg << 8) + cb2);
    }
  };
  auto genStore = [&](unsigned short* buf) {
    #pragma unroll
    for (int p = 0; p < 4; ++p) {
      const float rp_ = rb[p];
      unsigned d[4];
      float z0, z1;
      z0 = fmaf(-rp_, bflo(s_r[p].x), bflo(s_p[p].x) + bflo(s_q[p].x));
      z1 = fmaf(-rp_, bfhi(s_r[p].x), bfhi(s_p[p].x) + bfhi(s_q[p].x));
      d[0] = pk2(fmaxf(z0, 0.f), fmaxf(z1, 0.f));
      z0 = fmaf(-rp_, bflo(s_r[p].y), bflo(s_p[p].y) + bflo(s_q[p].y));
      z1 = fmaf(-rp_, bfhi(s_r[p].y), bfhi(s_p[p].y) + bfhi(s_q[p].y));
      d[1] = pk2(fmaxf(z0, 0.f), fmaxf(z1, 0.f));
      z0 = fmaf(-rp_, bflo(s_r[p].z), bflo(s_p[p].z) + bflo(s_q[p].z));
      z1 = fmaf(-rp_, bfhi(s_r[p].z), bfhi(s_p[p].z) + bfhi(s_q[p].z));
      d[2] = pk2(fmaxf(z0, 0.f), fmaxf(z1, 0.f));
      z0 = fmaf(-rp_, bflo(s_r[p].w), bflo(s_p[p].w) + bflo(s_q[p].w));
      z1 = fmaf(-rp_, bfhi(s_r[p].w), bfhi(s_p[p].w) + bfhi(s_q[p].w));
      d[3] = pk2(fmaxf(z0, 0.f), fmaxf(z1, 0.f));
      // fragment group id = p*256 + t (== ((mi*2+ks_id)*4+lq)*16+ln, mi=p*2+hi_id)
      *(uint4*)(&buf[(size_t)(p * 256 + t) * 8]) = make_uint4(d[0], d[1], d[2], d[3]);
    }
  };
  auto loadB = [&](int c, int ks, short8 (&bfr)[4]) {
    #pragma unroll
    for (int nj = 0; nj < 4; ++nj)
      bfr[nj] = *(const short8*)(W2t + (size_t)(w * 64 + nj * 16 + ln) * 512 +
                                 c * 64 + ks * 32 + lq * 8);
  };
  auto mfma_half = [&](const unsigned short* buf, int ks, short8 (&bfr)[4]) {
    short8 afr[4];
    #pragma unroll
    for (int mi = 0; mi < 4; ++mi)
      afr[mi] = *(const short8*)(buf + (size_t)((((mi * 2 + ks) * 4 + lq) * 16 + ln) * 8));
    #pragma unroll
    for (int mi = 0; mi < 4; ++mi)
      #pragma unroll
      for (int nj = 0; nj < 4; ++nj)
        acc[mi][nj] = __builtin_amdgcn_mfma_f32_16x16x32_bf16(afr[mi], bfr[nj], acc[mi][nj], 0, 0, 0);
    #pragma unroll
    for (int mi = 0; mi < 4; ++mi)
      afr[mi] = *(const short8*)(buf + (size_t)(((((mi + 4) * 2 + ks) * 4 + lq) * 16 + ln) * 8));
    #pragma unroll
    for (int mi = 0; mi < 4; ++mi)
      #pragma unroll
      for (int nj = 0; nj < 4; ++nj)
        acc[mi + 4][nj] = __builtin_amdgcn_mfma_f32_16x16x32_bf16(afr[mi], bfr[nj], acc[mi + 4][nj], 0, 0, 0);
  };

  // prologue: chunk0 staged (one-time vmcnt stall); chunk1 loads + both bfr(0,*) in flight
  genLoad(0);
  genStore(A_lds[0]);
  genLoad(1);
  loadB(0, 0, bfr0);
  loadB(0, 1, bfr1);

  for (int c = 0; c < 8; ++c) {
    __syncthreads();  // writes of buf[c&1] visible; prior reads of buf[(c+1)&1] done
    if (c < 7) genStore(A_lds[(c + 1) & 1]);  // data loaded a full chunk ago
    if (c < 6) genLoad(c + 2);                // newest in queue; MFMA waits skip it
    const unsigned short* buf = A_lds[c & 1];
    mfma_half(buf, 0, bfr0);
    if (c < 7) loadB(c + 1, 0, bfr0);         // issue a full chunk before use
    mfma_half(buf, 1, bfr1);
    if (c < 7) loadB(c + 1, 1, bfr1);
  }

  // epilogue: u = relu(t2[o]*acc + c2[o]) * W3[o]; reduce over o
  float t2v[4], c2v[4], w3v[4];
  #pragma unroll
  for (int nj = 0; nj < 4; ++nj) {
    int o = w * 64 + nj * 16 + ln;
    t2v[nj] = t2[o];
    c2v[nj] = c2[o];
    w3v[nj] = W3[o];
  }
  #pragma unroll
  for (int mi = 0; mi < 8; ++mi) {
    float s[4] = {0.f, 0.f, 0.f, 0.f};
    #pragma unroll
    for (int nj = 0; nj < 4; ++nj)
      #pragma unroll
      for (int r = 0; r < 4; ++r) {
        float u = fmaf(t2v[nj], acc[mi][nj][r], c2v[nj]);
        u = fmaxf(u, 0.f);
        s[r] = fmaf(u, w3v[nj], s[r]);
      }
    #pragma unroll
    for (int r = 0; r < 4; ++r) {
      #pragma unroll
      for (int m = 1; m < 16; m <<= 1) s[r] += __shfl_xor(s[r], m, 64);
    }
    if (ln == 0) {
      #pragma unroll
      for (int r = 0; r < 4; ++r) partial[w][mi * 16 + lq * 4 + r] = s[r];
    }
  }
  __syncthreads();
  if (t < 128) {
    out[(t & 63) * 2048 + k0 + (t >> 6)] =
        partial[0][t] + partial[1][t] + partial[2][t] + partial[3][t] + b3[0];
  }
}

extern "C" void kernel_launch(void* const* d_in, const int* in_sizes, int n_in,
                              void* d_out, int out_size, void* d_ws, size_t ws_size,
                              hipStream_t stream) {
  const float* rep   = (const float*)d_in[0];
  const float* emb   = (const float*)d_in[1];
  const float* W1    = (const float*)d_in[2];
  const float* b1    = (const float*)d_in[3];
  const float* g1    = (const float*)d_in[4];
  const float* beta1 = (const float*)d_in[5];
  const float* m1    = (const float*)d_in[6];
  const float* v1    = (const float*)d_in[7];
  const float* W2    = (const float*)d_in[8];
  const float* b2    = (const float*)d_in[9];
  const float* g2    = (const float*)d_in[10];
  const float* beta2 = (const float*)d_in[11];
  const float* m2    = (const float*)d_in[12];
  const float* v2    = (const float*)d_in[13];
  const float* W3    = (const float*)d_in[14];
  const float* b3    = (const float*)d_in[15];
  float* out = (float*)d_out;
  char* ws = (char*)d_ws;

  float* Pf            = (float*)(ws + 0);           // 64x512 f32 (128 KB)
  unsigned* P          = (unsigned*)(ws + 131072);   // 64x256 bf16 pairs (64 KB)
  unsigned* Q          = (unsigned*)(ws + 196608);   // 2048x256 pairs (2 MB)
  unsigned* R          = (unsigned*)(ws + 2293760);  // 2048x256 pairs (2 MB)
  unsigned short* W2t  = (unsigned short*)(ws + 4390912);  // 256x512 bf16 (256 KB)
  float* t2            = (float*)(ws + 4653056);     // 256 f32
  float* c2            = (float*)(ws + 4654080);     // 256 f32

  prep2<<<577, 256, 0, stream>>>(emb, W1, g1, v1, b1, m1, beta1, W2, g2, v2,
                                 b2, m2, beta2, Q, R, W2t, t2, c2, Pf);
  p_gemm<<<512, 256, 0, stream>>>(rep, R, Pf);
  pf2p<<<64, 256, 0, stream>>>(Pf, P);
  fused_main<<<1024, 256, 0, stream>>>(rep, P, Q, R, W2t, t2, c2, W3, b3, out);
}